// Round 21
// baseline (58.982 us; speedup 1.0000x reference)
//
#include <hip/hip_runtime.h>
#include <hip/hip_bf16.h>

#define NN 2048
#define NH 12
#define HD 32
#define CALL 384   // NH*HD == OUT

typedef float f32x16 __attribute__((ext_vector_type(16)));
typedef _Float16 f16x4 __attribute__((ext_vector_type(4)));
typedef __fp16 fp16x2 __attribute__((ext_vector_type(2)));

static __device__ __forceinline__ f32x16 mfma8f16(f16x4 a, f16x4 b, f32x16 c) {
    return __builtin_amdgcn_mfma_f32_32x32x8f16(a, b, c, 0, 0, 0);
}
static __device__ __forceinline__ f16x4 u2f(uint2 u) {
    union { uint2 u2; f16x4 f; } c; c.u2 = u; return c.f;
}
// zero-VGPR async global->LDS copy, 16B per lane (dest = wave base + lane*16)
static __device__ __forceinline__ void gload16(const void* gp, void* lp) {
    __builtin_amdgcn_global_load_lds(
        (const __attribute__((address_space(1))) unsigned int*)gp,
        (__attribute__((address_space(3))) unsigned int*)lp, 16, 0, 0);
}

// ---------------------------------------------------------------------------
// gemm01 (R17 best): fused first two GEMMs, K-SPLIT 8-wave blocks + T14.
// z=0: h = x W^T -> outT (f16 [384][2048]) + FUSED srcdst
// z=1: res = x resW^T -> outF (f32 [2048][384]) + bias
// ---------------------------------------------------------------------------
__global__ __launch_bounds__(512) void gemm01(
    const float* __restrict__ A, const float* __restrict__ B0,
    const float* __restrict__ B1, const float* __restrict__ bias1,
    const float* __restrict__ attn_src, const float* __restrict__ attn_dst,
    _Float16* __restrict__ outT, float* __restrict__ outF,
    float* __restrict__ asrc, float* __restrict__ adstT)
{
    __shared__ __align__(16) char smem[17408];
    _Float16 (*As)[68] = (_Float16(*)[68])(smem);
    _Float16 (*Bs)[68] = (_Float16(*)[68])(smem + 8704);
    float* red = (float*)smem;

    const int t = threadIdx.x;
    const int w = t >> 6, l = t & 63, g = l >> 5, il = l & 31;
    const int q = w & 3, kg = w >> 2;
    const int m0 = blockIdx.x * 64, n0 = blockIdx.y * 64;
    const int mode = blockIdx.z;
    const float* B = mode ? B1 : B0;
    const int wr = (q >> 1) * 32, wc = (q & 1) * 32;
    const int ti = t >> 3, seg = t & 7;
    const int Kdim = 256;

    const float* Abase = A + (size_t)(m0 + ti) * Kdim + seg * 8;
    const float* Bbase = B + (size_t)(n0 + ti) * Kdim + seg * 8;

    f32x16 acc;
#pragma unroll
    for (int r = 0; r < 16; ++r) acc[r] = 0.f;

    float4 av0 = *reinterpret_cast<const float4*>(Abase);
    float4 av1 = *reinterpret_cast<const float4*>(Abase + 4);
    float4 bv0 = *reinterpret_cast<const float4*>(Bbase);
    float4 bv1 = *reinterpret_cast<const float4*>(Bbase + 4);

#pragma unroll 1
    for (int ss = 0; ss < 4; ++ss) {
        __syncthreads();
        {
            f16x4 lo = {(_Float16)av0.x, (_Float16)av0.y, (_Float16)av0.z, (_Float16)av0.w};
            f16x4 hi = {(_Float16)av1.x, (_Float16)av1.y, (_Float16)av1.z, (_Float16)av1.w};
            *reinterpret_cast<f16x4*>(&As[ti][seg * 8])     = lo;
            *reinterpret_cast<f16x4*>(&As[ti][seg * 8 + 4]) = hi;
            f16x4 lo2 = {(_Float16)bv0.x, (_Float16)bv0.y, (_Float16)bv0.z, (_Float16)bv0.w};
            f16x4 hi2 = {(_Float16)bv1.x, (_Float16)bv1.y, (_Float16)bv1.z, (_Float16)bv1.w};
            *reinterpret_cast<f16x4*>(&Bs[ti][seg * 8])     = lo2;
            *reinterpret_cast<f16x4*>(&Bs[ti][seg * 8 + 4]) = hi2;
        }
        __syncthreads();
        if (ss < 3) {
            const int kk = (ss + 1) * 64;
            av0 = *reinterpret_cast<const float4*>(Abase + kk);
            av1 = *reinterpret_cast<const float4*>(Abase + kk + 4);
            bv0 = *reinterpret_cast<const float4*>(Bbase + kk);
            bv1 = *reinterpret_cast<const float4*>(Bbase + kk + 4);
        }
#pragma unroll
        for (int kc = 0; kc < 4; ++kc) {
            f16x4 af = *reinterpret_cast<const f16x4*>(&As[wr + il][kg * 32 + kc * 8 + 4 * g]);
            f16x4 bf = *reinterpret_cast<const f16x4*>(&Bs[wc + il][kg * 32 + kc * 8 + 4 * g]);
            acc = mfma8f16(af, bf, acc);
        }
    }

    __syncthreads();
    if (kg == 1) {
#pragma unroll
        for (int r = 0; r < 16; ++r) red[(q * 16 + r) * 64 + l] = acc[r];
    }
    __syncthreads();
    if (kg != 0) return;
#pragma unroll
    for (int r = 0; r < 16; ++r) acc[r] += red[(q * 16 + r) * 64 + l];

    const int colg = n0 + wc + il;
    if (mode == 0) {
#pragma unroll
        for (int p = 0; p < 4; ++p) {
            const int row = m0 + wr + 8 * p + 4 * g;
            f16x4 v;
#pragma unroll
            for (int r = 0; r < 4; ++r) v[r] = (_Float16)acc[4 * p + r];
            *reinterpret_cast<f16x4*>(&outT[(size_t)colg * NN + row]) = v;
        }
        const int hstar = colg >> 5;
        const float sv = attn_src[hstar * HD + il];
        const float dv = attn_dst[hstar * HD + il];
        float ps[16], pd[16];
#pragma unroll
        for (int r = 0; r < 16; ++r) { ps[r] = acc[r] * sv; pd[r] = acc[r] * dv; }
#pragma unroll
        for (int m = 1; m <= 16; m <<= 1) {
#pragma unroll
            for (int r = 0; r < 16; ++r) {
                ps[r] += __shfl_xor(ps[r], m);
                pd[r] += __shfl_xor(pd[r], m);
            }
        }
        if (il == 0) {
#pragma unroll
            for (int r = 0; r < 16; ++r) {
                const int row = m0 + wr + (r & 3) + 8 * (r >> 2) + 4 * g;
                asrc[row * NH + hstar] = ps[r];
                adstT[(size_t)hstar * NN + row] = pd[r] * 1.44269504089f;
            }
        }
    } else {
        const float bs = bias1[colg];
#pragma unroll
        for (int r = 0; r < 16; ++r) {
            const int row = m0 + wr + (r & 3) + 8 * (r >> 2) + 4 * g;
            outF[(size_t)row * CALL + colg] = acc[r] + bs;
        }
    }
}

// ---------------------------------------------------------------------------
// gemm2 (R17 best): final GEMM (K=384), K-SPLIT + T14. + bias + exact GELU.
// ---------------------------------------------------------------------------
__global__ __launch_bounds__(512) void gemm2(
    const _Float16* __restrict__ A16, const float* __restrict__ B,
    const float* __restrict__ bias, float* __restrict__ outF)
{
    __shared__ __align__(16) char smem[17408];
    _Float16 (*As)[68] = (_Float16(*)[68])(smem);
    _Float16 (*Bs)[68] = (_Float16(*)[68])(smem + 8704);
    float* red = (float*)smem;

    const int t = threadIdx.x;
    const int w = t >> 6, l = t & 63, g = l >> 5, il = l & 31;
    const int q = w & 3, kg = w >> 2;
    const int m0 = blockIdx.x * 64, n0 = blockIdx.y * 64;
    const int wr = (q >> 1) * 32, wc = (q & 1) * 32;
    const int ti = t >> 3, seg = t & 7;
    const int Kdim = 384;

    const _Float16* Abase = A16 + (size_t)(m0 + ti) * Kdim + seg * 8;
    const float*    Bbase = B   + (size_t)(n0 + ti) * Kdim + seg * 8;

    f32x16 acc;
#pragma unroll
    for (int r = 0; r < 16; ++r) acc[r] = 0.f;

    uint4  av = *reinterpret_cast<const uint4*>(Abase);
    float4 bv0 = *reinterpret_cast<const float4*>(Bbase);
    float4 bv1 = *reinterpret_cast<const float4*>(Bbase + 4);

#pragma unroll 1
    for (int ss = 0; ss < 6; ++ss) {
        __syncthreads();
        {
            *reinterpret_cast<uint2*>(&As[ti][seg * 8])     = make_uint2(av.x, av.y);
            *reinterpret_cast<uint2*>(&As[ti][seg * 8 + 4]) = make_uint2(av.z, av.w);
            f16x4 lo = {(_Float16)bv0.x, (_Float16)bv0.y, (_Float16)bv0.z, (_Float16)bv0.w};
            f16x4 hi = {(_Float16)bv1.x, (_Float16)bv1.y, (_Float16)bv1.z, (_Float16)bv1.w};
            *reinterpret_cast<f16x4*>(&Bs[ti][seg * 8])     = lo;
            *reinterpret_cast<f16x4*>(&Bs[ti][seg * 8 + 4]) = hi;
        }
        __syncthreads();
        if (ss < 5) {
            const int kk = (ss + 1) * 64;
            av  = *reinterpret_cast<const uint4*>(Abase + kk);
            bv0 = *reinterpret_cast<const float4*>(Bbase + kk);
            bv1 = *reinterpret_cast<const float4*>(Bbase + kk + 4);
        }
#pragma unroll
        for (int kc = 0; kc < 4; ++kc) {
            f16x4 af = *reinterpret_cast<const f16x4*>(&As[wr + il][kg * 32 + kc * 8 + 4 * g]);
            f16x4 bf = *reinterpret_cast<const f16x4*>(&Bs[wc + il][kg * 32 + kc * 8 + 4 * g]);
            acc = mfma8f16(af, bf, acc);
        }
    }

    __syncthreads();
    if (kg == 1) {
#pragma unroll
        for (int r = 0; r < 16; ++r) red[(q * 16 + r) * 64 + l] = acc[r];
    }
    __syncthreads();
    if (kg != 0) return;
#pragma unroll
    for (int r = 0; r < 16; ++r) acc[r] += red[(q * 16 + r) * 64 + l];

    const int colg = n0 + wc + il;
    const float bs = bias[colg];
#pragma unroll
    for (int r = 0; r < 16; ++r) {
        const int row = m0 + wr + (r & 3) + 8 * (r >> 2) + 4 * g;
        float vv = acc[r] + bs;
        vv = 0.5f * vv * (1.0f + erff(vv * 0.70710678118f));
        outF[(size_t)row * CALL + colg] = vv;
    }
}

// ---------------------------------------------------------------------------
// attn18: ONE HEAD PER WAVE at 6 waves/SIMD (acc=16 VGPR), with XCD-GROUPED
// block swizzle fixing R9's cross-XCD adj re-fetch. Grid 768 = 64 bands x 12
// heads; blocks with b&7==k land on XCD k (round-robin dispatch) and cover
// bands 8k..8k+7 x all heads -> per-XCD L2 working set = adj 2MB + hT 1.5MB
// + adstT 0.1MB < 4MB. 512 thr = 8 waves, wave owns j-chunk 256 (8 tiles).
// adj via zero-VGPR global_load_lds prefetched 1 tile ahead (attn15's
// FIFO-safe order: hT loads issued BEFORE next-tile DMAs). adst in
// wave-private LDS. Epilogue = attn12's verified 8-wave 2-phase reduce.
// 3 blocks/CU co-resident (LDS 40KB, VGPR<=85 via (512,6)).
// ---------------------------------------------------------------------------
__global__ __launch_bounds__(512, 6) void attn18(
    const float* __restrict__ adj, const _Float16* __restrict__ hT,
    const float* __restrict__ asrc, const float* __restrict__ adstT,
    const float* __restrict__ eW, const float* __restrict__ eb,
    const float* __restrict__ res, _Float16* __restrict__ hsum)
{
    // per-wave slice at w*5120: adj_buf 4096B | adst 1024B (8 waves = 40960B)
    // epilogue overlay: red[4][16][64] f32 (16384B) at 0 | dsum_s[8][32] at 16384
    __shared__ __align__(16) char smem[40960];
    const int t = threadIdx.x;
    const int w = t >> 6, l = t & 63, g = l >> 5, il = l & 31;
    const int b = blockIdx.x;
    const int xcd = b & 7, qq = b >> 3;          // qq in [0,96)
    const int h = qq % NH, bw = qq / NH;         // head, band-within-xcd
    const int band = xcd * 8 + bw;
    const int i0 = band * 32, c0 = h * 32;

    char* slice   = smem + w * 5120;
    char* adjb    = slice;                       // 4 KB adj tile buffer
    float* adst_s = (float*)(slice + 4096);
    float* red    = (float*)smem;
    float* dsum_s = (float*)(smem + 16384);

    const float LOG2E = 1.44269504089f;
    const int jbase = w * 256;
    const float* abase = adj + (size_t)(i0 + il) * NN + jbase + 16 * g;  // per-lane

    // issue tile-0 adj prefetch immediately (latency overlaps prologue)
#pragma unroll
    for (int p = 0; p < 4; ++p)
        gload16(abase + 4 * p, adjb + p * 1024);

    const float base = (asrc[(size_t)(i0 + il) * NH + h] + eb[h]) * LOG2E;
    const float eWr  = eW[h] * LOG2E;
#pragma unroll
    for (int p = 0; p < 4; ++p)
        adst_s[p * 64 + l] = adstT[(size_t)h * NN + jbase + p * 64 + l];

    f32x16 acc;
#pragma unroll
    for (int r = 0; r < 16; ++r) acc[r] = 0.f;
    float4 dsumv = make_float4(0.f, 0.f, 0.f, 0.f);

    const _Float16* hbase = hT + (size_t)(c0 + il) * NN + jbase + 16 * g;

#pragma unroll 1
    for (int tl = 0; tl < 8; ++tl) {
        const int jo = tl * 32;
        // adj(tl) has landed once outstanding vmem (prefetch gloads) drains
        asm volatile("s_waitcnt vmcnt(0)" ::: "memory");
        const float4 aj0 = *reinterpret_cast<const float4*>(adjb + 0 * 1024 + l * 16);
        const float4 aj1 = *reinterpret_cast<const float4*>(adjb + 1 * 1024 + l * 16);
        const float4 aj2 = *reinterpret_cast<const float4*>(adjb + 2 * 1024 + l * 16);
        const float4 aj3 = *reinterpret_cast<const float4*>(adjb + 3 * 1024 + l * 16);
        asm volatile("s_waitcnt lgkmcnt(0)" ::: "memory");
        __builtin_amdgcn_sched_barrier(0);
        // hT loads FIRST (older in vmcnt FIFO than next-tile DMAs)
        const _Float16* hp = hbase + jo;
        const uint4 hA = *reinterpret_cast<const uint4*>(hp);      // j [16g,16g+8)
        const uint4 hB = *reinterpret_cast<const uint4*>(hp + 8);  // j [16g+8,16g+16)
        __builtin_amdgcn_sched_barrier(0);
        if (tl < 7) {
#pragma unroll
            for (int p = 0; p < 4; ++p)
                gload16(abase + jo + 32 + 4 * p, adjb + p * 1024);
        }
        __builtin_amdgcn_sched_barrier(0);
#pragma unroll
        for (int ks = 0; ks < 4; ++ks) {
            const float4 a4 = (ks == 0) ? aj0 : (ks == 1) ? aj1 : (ks == 2) ? aj2 : aj3;
            const float4 ad = *reinterpret_cast<const float4*>(
                &adst_s[jo + 16 * g + 4 * ks]);
            float e0, e1, e2, e3;
#pragma unroll
            for (int jj = 0; jj < 4; ++jj) {
                const float ajv = (&a4.x)[jj];
                float tt = fmaf(ajv, eWr, base + (&ad.x)[jj]);
                tt = fmaxf(tt, 0.2f * tt);
                const float ee = ajv > 0.f ? __builtin_amdgcn_exp2f(tt) : 0.f;
                (&dsumv.x)[jj] += ee;
                (jj == 0 ? e0 : jj == 1 ? e1 : jj == 2 ? e2 : e3) = ee;
            }
            union { fp16x2 h2[2]; f16x4 h4; } u;
            u.h2[0] = __builtin_amdgcn_cvt_pkrtz(e0, e1);
            u.h2[1] = __builtin_amdgcn_cvt_pkrtz(e2, e3);
            const uint2 hu = (ks == 0) ? make_uint2(hA.x, hA.y)
                           : (ks == 1) ? make_uint2(hA.z, hA.w)
                           : (ks == 2) ? make_uint2(hB.x, hB.y)
                                       : make_uint2(hB.z, hB.w);
            acc = mfma8f16(u.h4, u2f(hu), acc);
        }
    }

    // ---- epilogue: 2-phase cross-wave reduce (8 waves -> 4-wave region) ----
    __syncthreads();   // all waves done with slices; overlay is safe
    {
        float dt = (dsumv.x + dsumv.y) + (dsumv.z + dsumv.w);
        dt += __shfl_xor(dt, 32);
        if (g == 0) dsum_s[w * 32 + il] = dt;
    }
    if (w < 4) {
#pragma unroll
        for (int r = 0; r < 16; ++r) red[(w * 16 + r) * 64 + l] = acc[r];
    }
    __syncthreads();
    if (w >= 4) {
#pragma unroll
        for (int r = 0; r < 16; ++r) red[((w - 4) * 16 + r) * 64 + l] += acc[r];
    }
    __syncthreads();

    // output: wave w handles acc registers w and w+8
#pragma unroll
    for (int rr = 0; rr < 2; ++rr) {
        const int reg = w + rr * 8;
        const int row_off = (reg & 3) + 8 * (reg >> 2) + 4 * g;
        const int row = i0 + row_off;
        float v = 0.f, d = 0.f;
#pragma unroll
        for (int p = 0; p < 4; ++p)
            v += red[(p * 16 + reg) * 64 + l];
#pragma unroll
        for (int ww = 0; ww < 8; ++ww)
            d += dsum_s[ww * 32 + row_off];
        const float inv = __builtin_amdgcn_rcpf(d);
        const int col = c0 + il;
        hsum[(size_t)row * CALL + col] = (_Float16)(v * inv + res[(size_t)row * CALL + col]);
    }
}

extern "C" void kernel_launch(void* const* d_in, const int* in_sizes, int n_in,
                              void* d_out, int out_size, void* d_ws, size_t ws_size,
                              hipStream_t stream)
{
    const float* x        = (const float*)d_in[0];
    const float* adj      = (const float*)d_in[1];
    const float* W        = (const float*)d_in[2];
    const float* attn_src = (const float*)d_in[3];
    const float* attn_dst = (const float*)d_in[4];
    const float* edge_W   = (const float*)d_in[5];
    const float* edge_b   = (const float*)d_in[6];
    const float* res_W    = (const float*)d_in[7];
    const float* res_b    = (const float*)d_in[8];
    const float* fus_W    = (const float*)d_in[9];
    const float* fus_b    = (const float*)d_in[10];
    float* out = (float*)d_out;

    char* ws = (char*)d_ws;
    size_t off = 0;
    auto alloc = [&](size_t bytes) { void* p = ws + off; off = (off + bytes + 255) & ~(size_t)255; return p; };
    _Float16* hT    = (_Float16*)alloc((size_t)CALL * NN * 2);
    float*    res   = (float*)alloc((size_t)NN * CALL * 4);
    float*    asrc  = (float*)alloc((size_t)NN * NH * 4);
    float*    adstT = (float*)alloc((size_t)NH * NN * 4);
    _Float16* hsum  = (_Float16*)alloc((size_t)NN * CALL * 2);
    (void)ws_size;

    gemm01<<<dim3(32, 6, 2), dim3(512), 0, stream>>>(x, W, res_W, res_b, attn_src, attn_dst, hT, res, asrc, adstT);
    attn18<<<768, dim3(512), 0, stream>>>(adj, hT, asrc, adstT, edge_W, edge_b, res, hsum);
    gemm2<<<dim3(32, 6), dim3(512), 0, stream>>>(hsum, fus_W, fus_b, out);
}

// Round 22
// 46.230 us; speedup vs baseline: 1.2758x; 1.2758x over previous
//
#include <hip/hip_runtime.h>
#include <hip/hip_bf16.h>

#define NN 2048
#define NH 12
#define HD 32
#define CALL 384   // NH*HD == OUT

typedef float f32x16 __attribute__((ext_vector_type(16)));
typedef _Float16 f16x4 __attribute__((ext_vector_type(4)));
typedef __fp16 fp16x2 __attribute__((ext_vector_type(2)));

static __device__ __forceinline__ f32x16 mfma8f16(f16x4 a, f16x4 b, f32x16 c) {
    return __builtin_amdgcn_mfma_f32_32x32x8f16(a, b, c, 0, 0, 0);
}
static __device__ __forceinline__ f16x4 u2f(uint2 u) {
    union { uint2 u2; f16x4 f; } c; c.u2 = u; return c.f;
}
// zero-VGPR async global->LDS copy, 16B per lane (dest = wave base + lane*16)
static __device__ __forceinline__ void gload16(const void* gp, void* lp) {
    __builtin_amdgcn_global_load_lds(
        (const __attribute__((address_space(1))) unsigned int*)gp,
        (__attribute__((address_space(3))) unsigned int*)lp, 16, 0, 0);
}

// hF layout: [jt(64)][head(12)][ks(4)][lane(64)*8B]  -- lane l's 8B IS its
// MFMA B-fragment for (jtile, head, ks): j = 16*(l>>5) + 4*ks + e, d = l&31.
// A consumer load is 512B contiguous (8 cache lines) vs 32-64 lines for the
// old row-strided hT reads (TA line-throughput was the binding constraint).

// ---------------------------------------------------------------------------
// gemm01: fused first two GEMMs, K-SPLIT 8-wave blocks + T14.
// z=0: h = x W^T -> hF (fragment-major scatter) + FUSED srcdst
// z=1: res = x resW^T -> outF (f32 [2048][384]) + bias
// ---------------------------------------------------------------------------
__global__ __launch_bounds__(512) void gemm01(
    const float* __restrict__ A, const float* __restrict__ B0,
    const float* __restrict__ B1, const float* __restrict__ bias1,
    const float* __restrict__ attn_src, const float* __restrict__ attn_dst,
    _Float16* __restrict__ hF, float* __restrict__ outF,
    float* __restrict__ asrc, float* __restrict__ adstT)
{
    __shared__ __align__(16) char smem[17408];
    _Float16 (*As)[68] = (_Float16(*)[68])(smem);
    _Float16 (*Bs)[68] = (_Float16(*)[68])(smem + 8704);
    float* red = (float*)smem;

    const int t = threadIdx.x;
    const int w = t >> 6, l = t & 63, g = l >> 5, il = l & 31;
    const int q = w & 3, kg = w >> 2;
    const int m0 = blockIdx.x * 64, n0 = blockIdx.y * 64;
    const int mode = blockIdx.z;
    const float* B = mode ? B1 : B0;
    const int wr = (q >> 1) * 32, wc = (q & 1) * 32;
    const int ti = t >> 3, seg = t & 7;
    const int Kdim = 256;

    const float* Abase = A + (size_t)(m0 + ti) * Kdim + seg * 8;
    const float* Bbase = B + (size_t)(n0 + ti) * Kdim + seg * 8;

    f32x16 acc;
#pragma unroll
    for (int r = 0; r < 16; ++r) acc[r] = 0.f;

    float4 av0 = *reinterpret_cast<const float4*>(Abase);
    float4 av1 = *reinterpret_cast<const float4*>(Abase + 4);
    float4 bv0 = *reinterpret_cast<const float4*>(Bbase);
    float4 bv1 = *reinterpret_cast<const float4*>(Bbase + 4);

#pragma unroll 1
    for (int ss = 0; ss < 4; ++ss) {
        __syncthreads();
        {
            f16x4 lo = {(_Float16)av0.x, (_Float16)av0.y, (_Float16)av0.z, (_Float16)av0.w};
            f16x4 hi = {(_Float16)av1.x, (_Float16)av1.y, (_Float16)av1.z, (_Float16)av1.w};
            *reinterpret_cast<f16x4*>(&As[ti][seg * 8])     = lo;
            *reinterpret_cast<f16x4*>(&As[ti][seg * 8 + 4]) = hi;
            f16x4 lo2 = {(_Float16)bv0.x, (_Float16)bv0.y, (_Float16)bv0.z, (_Float16)bv0.w};
            f16x4 hi2 = {(_Float16)bv1.x, (_Float16)bv1.y, (_Float16)bv1.z, (_Float16)bv1.w};
            *reinterpret_cast<f16x4*>(&Bs[ti][seg * 8])     = lo2;
            *reinterpret_cast<f16x4*>(&Bs[ti][seg * 8 + 4]) = hi2;
        }
        __syncthreads();
        if (ss < 3) {
            const int kk = (ss + 1) * 64;
            av0 = *reinterpret_cast<const float4*>(Abase + kk);
            av1 = *reinterpret_cast<const float4*>(Abase + kk + 4);
            bv0 = *reinterpret_cast<const float4*>(Bbase + kk);
            bv1 = *reinterpret_cast<const float4*>(Bbase + kk + 4);
        }
#pragma unroll
        for (int kc = 0; kc < 4; ++kc) {
            f16x4 af = *reinterpret_cast<const f16x4*>(&As[wr + il][kg * 32 + kc * 8 + 4 * g]);
            f16x4 bf = *reinterpret_cast<const f16x4*>(&Bs[wc + il][kg * 32 + kc * 8 + 4 * g]);
            acc = mfma8f16(af, bf, acc);
        }
    }

    __syncthreads();
    if (kg == 1) {
#pragma unroll
        for (int r = 0; r < 16; ++r) red[(q * 16 + r) * 64 + l] = acc[r];
    }
    __syncthreads();
    if (kg != 0) return;
#pragma unroll
    for (int r = 0; r < 16; ++r) acc[r] += red[(q * 16 + r) * 64 + l];

    const int colg = n0 + wc + il;
    if (mode == 0) {
        const int hstar = colg >> 5;            // head; d = il
        // fragment-major scatter: element h[j][hstar*32+il] -> hF slot
#pragma unroll
        for (int r = 0; r < 16; ++r) {
            const int j = m0 + wr + (r & 3) + 8 * (r >> 2) + 4 * g;
            const int jt = j >> 5, jin = j & 31;
            const int g_f = jin >> 4, ks_f = (jin & 15) >> 2, e = jin & 3;
            const int lane_f = 32 * g_f + il;
            hF[(size_t)(((jt * NH + hstar) * 4 + ks_f) * 256) + lane_f * 4 + e] =
                (_Float16)acc[r];
        }
        const float sv = attn_src[hstar * HD + il];
        const float dv = attn_dst[hstar * HD + il];
        float ps[16], pd[16];
#pragma unroll
        for (int r = 0; r < 16; ++r) { ps[r] = acc[r] * sv; pd[r] = acc[r] * dv; }
#pragma unroll
        for (int m = 1; m <= 16; m <<= 1) {
#pragma unroll
            for (int r = 0; r < 16; ++r) {
                ps[r] += __shfl_xor(ps[r], m);
                pd[r] += __shfl_xor(pd[r], m);
            }
        }
        if (il == 0) {
#pragma unroll
            for (int r = 0; r < 16; ++r) {
                const int row = m0 + wr + (r & 3) + 8 * (r >> 2) + 4 * g;
                asrc[row * NH + hstar] = ps[r];
                adstT[(size_t)hstar * NN + row] = pd[r] * 1.44269504089f;
            }
        }
    } else {
        const float bs = bias1[colg];
#pragma unroll
        for (int r = 0; r < 16; ++r) {
            const int row = m0 + wr + (r & 3) + 8 * (r >> 2) + 4 * g;
            outF[(size_t)row * CALL + colg] = acc[r] + bs;
        }
    }
}

// ---------------------------------------------------------------------------
// gemm2 (R17 best): final GEMM (K=384), K-SPLIT + T14. + bias + exact GELU.
// ---------------------------------------------------------------------------
__global__ __launch_bounds__(512) void gemm2(
    const _Float16* __restrict__ A16, const float* __restrict__ B,
    const float* __restrict__ bias, float* __restrict__ outF)
{
    __shared__ __align__(16) char smem[17408];
    _Float16 (*As)[68] = (_Float16(*)[68])(smem);
    _Float16 (*Bs)[68] = (_Float16(*)[68])(smem + 8704);
    float* red = (float*)smem;

    const int t = threadIdx.x;
    const int w = t >> 6, l = t & 63, g = l >> 5, il = l & 31;
    const int q = w & 3, kg = w >> 2;
    const int m0 = blockIdx.x * 64, n0 = blockIdx.y * 64;
    const int wr = (q >> 1) * 32, wc = (q & 1) * 32;
    const int ti = t >> 3, seg = t & 7;
    const int Kdim = 384;

    const _Float16* Abase = A16 + (size_t)(m0 + ti) * Kdim + seg * 8;
    const float*    Bbase = B   + (size_t)(n0 + ti) * Kdim + seg * 8;

    f32x16 acc;
#pragma unroll
    for (int r = 0; r < 16; ++r) acc[r] = 0.f;

    uint4  av = *reinterpret_cast<const uint4*>(Abase);
    float4 bv0 = *reinterpret_cast<const float4*>(Bbase);
    float4 bv1 = *reinterpret_cast<const float4*>(Bbase + 4);

#pragma unroll 1
    for (int ss = 0; ss < 6; ++ss) {
        __syncthreads();
        {
            *reinterpret_cast<uint2*>(&As[ti][seg * 8])     = make_uint2(av.x, av.y);
            *reinterpret_cast<uint2*>(&As[ti][seg * 8 + 4]) = make_uint2(av.z, av.w);
            f16x4 lo = {(_Float16)bv0.x, (_Float16)bv0.y, (_Float16)bv0.z, (_Float16)bv0.w};
            f16x4 hi = {(_Float16)bv1.x, (_Float16)bv1.y, (_Float16)bv1.z, (_Float16)bv1.w};
            *reinterpret_cast<f16x4*>(&Bs[ti][seg * 8])     = lo;
            *reinterpret_cast<f16x4*>(&Bs[ti][seg * 8 + 4]) = hi;
        }
        __syncthreads();
        if (ss < 5) {
            const int kk = (ss + 1) * 64;
            av  = *reinterpret_cast<const uint4*>(Abase + kk);
            bv0 = *reinterpret_cast<const float4*>(Bbase + kk);
            bv1 = *reinterpret_cast<const float4*>(Bbase + kk + 4);
        }
#pragma unroll
        for (int kc = 0; kc < 4; ++kc) {
            f16x4 af = *reinterpret_cast<const f16x4*>(&As[wr + il][kg * 32 + kc * 8 + 4 * g]);
            f16x4 bf = *reinterpret_cast<const f16x4*>(&Bs[wc + il][kg * 32 + kc * 8 + 4 * g]);
            acc = mfma8f16(af, bf, acc);
        }
    }

    __syncthreads();
    if (kg == 1) {
#pragma unroll
        for (int r = 0; r < 16; ++r) red[(q * 16 + r) * 64 + l] = acc[r];
    }
    __syncthreads();
    if (kg != 0) return;
#pragma unroll
    for (int r = 0; r < 16; ++r) acc[r] += red[(q * 16 + r) * 64 + l];

    const int colg = n0 + wc + il;
    const float bs = bias[colg];
#pragma unroll
    for (int r = 0; r < 16; ++r) {
        const int row = m0 + wr + (r & 3) + 8 * (r >> 2) + 4 * g;
        float vv = acc[r] + bs;
        vv = 0.5f * vv * (1.0f + erff(vv * 0.70710678118f));
        outF[(size_t)row * CALL + colg] = vv;
    }
}

// ---------------------------------------------------------------------------
// attn19 = R20's attn17 with hT row-strided loads replaced by COALESCED
// fragment-major hF loads (8 lines per load vs 32-64). Everything else
// identical: adj zero-VGPR DMA prefetch, setprio, rcp epilogue.
// ---------------------------------------------------------------------------
__global__ __launch_bounds__(1024, 4) void attn19(
    const float* __restrict__ adj, const _Float16* __restrict__ hF,
    const float* __restrict__ asrc, const float* __restrict__ adstT,
    const float* __restrict__ eW, const float* __restrict__ eb,
    const float* __restrict__ res, _Float16* __restrict__ hsum)
{
    // per-wave slice at w*5632: adj_buf 4096B | adst 1536B
    // epilogue overlay: red[4][3][16][64] f32 (49152B) at 0 | dsum_s[16][3][32] at 49152
    __shared__ __align__(16) char smem[90112];
    const int t = threadIdx.x;
    const int w = t >> 6, l = t & 63, g = l >> 5, il = l & 31;
    const int band = blockIdx.x & 63, hg = blockIdx.x >> 6;
    const int i0 = band * 32, h0 = hg * 3;

    char* slice   = smem + w * 5632;
    char* adjb    = slice;                       // 4 KB adj tile buffer
    float* adst_s = (float*)(slice + 4096);
    float* red    = (float*)smem;
    float* dsum_s = (float*)(smem + 49152);

    const float LOG2E = 1.44269504089f;
    const int jbase = w * 128;
    const float* abase = adj + (size_t)(i0 + il) * NN + jbase + 16 * g;  // per-lane global

    // issue tile-0 adj prefetch immediately (latency overlaps prologue)
#pragma unroll
    for (int p = 0; p < 4; ++p)
        gload16(abase + 4 * p, adjb + p * 1024);

    float base_h[3], eWr[3];
#pragma unroll
    for (int hh = 0; hh < 3; ++hh) {
        base_h[hh] = (asrc[(size_t)(i0 + il) * NH + h0 + hh] + eb[h0 + hh]) * LOG2E;
        eWr[hh] = eW[h0 + hh] * LOG2E;
    }
#pragma unroll
    for (int p = 0; p < 6; ++p) {
        const int idx = p * 64 + l;
        adst_s[idx] = adstT[(size_t)(h0 + (idx >> 7)) * NN + jbase + (idx & 127)];
    }

    f32x16 acc[3];
#pragma unroll
    for (int hh = 0; hh < 3; ++hh)
#pragma unroll
        for (int r = 0; r < 16; ++r) acc[hh][r] = 0.f;
    float4 dsumv[3];
#pragma unroll
    for (int hh = 0; hh < 3; ++hh) dsumv[hh] = make_float4(0.f, 0.f, 0.f, 0.f);

#pragma unroll 1
    for (int tl = 0; tl < 4; ++tl) {
        const int jo = tl * 32;
        const int jt = w * 4 + tl;               // global 32-j tile index
        // adj(tl) has landed once outstanding vmem (prefetch gloads) drains
        asm volatile("s_waitcnt vmcnt(0)" ::: "memory");
        const float4 aj0 = *reinterpret_cast<const float4*>(adjb + 0 * 1024 + l * 16);
        const float4 aj1 = *reinterpret_cast<const float4*>(adjb + 1 * 1024 + l * 16);
        const float4 aj2 = *reinterpret_cast<const float4*>(adjb + 2 * 1024 + l * 16);
        const float4 aj3 = *reinterpret_cast<const float4*>(adjb + 3 * 1024 + l * 16);
        asm volatile("s_waitcnt lgkmcnt(0)" ::: "memory");
        __builtin_amdgcn_sched_barrier(0);
        // hF fragment loads FIRST (older in vmcnt FIFO than next-tile DMAs):
        // fully coalesced 512B blocks, lane l reads its own 8B fragment.
        uint2 hf[3][4];
#pragma unroll
        for (int hh = 0; hh < 3; ++hh) {
            const _Float16* fp = hF + (size_t)(((jt * NH + h0 + hh) * 4) * 256) + l * 4;
#pragma unroll
            for (int ks = 0; ks < 4; ++ks)
                hf[hh][ks] = *reinterpret_cast<const uint2*>(fp + ks * 256);
        }
        __builtin_amdgcn_sched_barrier(0);
        if (tl < 3) {
#pragma unroll
            for (int p = 0; p < 4; ++p)
                gload16(abase + jo + 32 + 4 * p, adjb + p * 1024);
        }
        __builtin_amdgcn_sched_barrier(0);
        __builtin_amdgcn_s_setprio(1);
#pragma unroll
        for (int hh = 0; hh < 3; ++hh) {
#pragma unroll
            for (int ks = 0; ks < 4; ++ks) {
                const float4 a4 = (ks == 0) ? aj0 : (ks == 1) ? aj1 : (ks == 2) ? aj2 : aj3;
                const float4 ad = *reinterpret_cast<const float4*>(
                    &adst_s[hh * 128 + jo + 16 * g + 4 * ks]);
                float e0, e1, e2, e3;
#pragma unroll
                for (int jj = 0; jj < 4; ++jj) {
                    const float ajv = (&a4.x)[jj];
                    float tt = fmaf(ajv, eWr[hh], base_h[hh] + (&ad.x)[jj]);
                    tt = fmaxf(tt, 0.2f * tt);
                    const float ee = ajv > 0.f ? __builtin_amdgcn_exp2f(tt) : 0.f;
                    (&dsumv[hh].x)[jj] += ee;
                    (jj == 0 ? e0 : jj == 1 ? e1 : jj == 2 ? e2 : e3) = ee;
                }
                union { fp16x2 h2[2]; f16x4 h4; } u;
                u.h2[0] = __builtin_amdgcn_cvt_pkrtz(e0, e1);
                u.h2[1] = __builtin_amdgcn_cvt_pkrtz(e2, e3);
                acc[hh] = mfma8f16(u.h4, u2f(hf[hh][ks]), acc[hh]);
            }
        }
        __builtin_amdgcn_s_setprio(0);
    }

    // ---- epilogue: phased cross-wave reduce (16 waves -> 4-wave red region) ----
    __syncthreads();
#pragma unroll
    for (int hh = 0; hh < 3; ++hh) {
        const float ds = (dsumv[hh].x + dsumv[hh].y) + (dsumv[hh].z + dsumv[hh].w);
        const float dtot = ds + __shfl_xor(ds, 32);
        if (g == 0) dsum_s[(w * 3 + hh) * 32 + il] = dtot;
    }
    if (w < 4) {
#pragma unroll
        for (int hh = 0; hh < 3; ++hh)
#pragma unroll
            for (int reg = 0; reg < 16; ++reg)
                red[((w * 3 + hh) * 16 + reg) * 64 + l] = acc[hh][reg];
    }
    __syncthreads();
    if (w >= 4 && w < 8) {
#pragma unroll
        for (int hh = 0; hh < 3; ++hh)
#pragma unroll
            for (int reg = 0; reg < 16; ++reg)
                red[(((w - 4) * 3 + hh) * 16 + reg) * 64 + l] += acc[hh][reg];
    }
    __syncthreads();
    if (w >= 8 && w < 12) {
#pragma unroll
        for (int hh = 0; hh < 3; ++hh)
#pragma unroll
            for (int reg = 0; reg < 16; ++reg)
                red[(((w - 8) * 3 + hh) * 16 + reg) * 64 + l] += acc[hh][reg];
    }
    __syncthreads();
    if (w >= 12) {
#pragma unroll
        for (int hh = 0; hh < 3; ++hh)
#pragma unroll
            for (int reg = 0; reg < 16; ++reg)
                red[(((w - 12) * 3 + hh) * 16 + reg) * 64 + l] += acc[hh][reg];
    }
    __syncthreads();

    {
        const int reg = w;
        const int row_off = (reg & 3) + 8 * (reg >> 2) + 4 * g;
        const int row = i0 + row_off;
#pragma unroll
        for (int hh = 0; hh < 3; ++hh) {
            float v = 0.f, d = 0.f;
#pragma unroll
            for (int p = 0; p < 4; ++p)
                v += red[((p * 3 + hh) * 16 + reg) * 64 + l];
#pragma unroll
            for (int ww = 0; ww < 16; ++ww)
                d += dsum_s[(ww * 3 + hh) * 32 + row_off];
            const float inv = __builtin_amdgcn_rcpf(d);
            const int col = (h0 + hh) * 32 + il;
            hsum[(size_t)row * CALL + col] = (_Float16)(v * inv + res[(size_t)row * CALL + col]);
        }
    }
}

extern "C" void kernel_launch(void* const* d_in, const int* in_sizes, int n_in,
                              void* d_out, int out_size, void* d_ws, size_t ws_size,
                              hipStream_t stream)
{
    const float* x        = (const float*)d_in[0];
    const float* adj      = (const float*)d_in[1];
    const float* W        = (const float*)d_in[2];
    const float* attn_src = (const float*)d_in[3];
    const float* attn_dst = (const float*)d_in[4];
    const float* edge_W   = (const float*)d_in[5];
    const float* edge_b   = (const float*)d_in[6];
    const float* res_W    = (const float*)d_in[7];
    const float* res_b    = (const float*)d_in[8];
    const float* fus_W    = (const float*)d_in[9];
    const float* fus_b    = (const float*)d_in[10];
    float* out = (float*)d_out;

    char* ws = (char*)d_ws;
    size_t off = 0;
    auto alloc = [&](size_t bytes) { void* p = ws + off; off = (off + bytes + 255) & ~(size_t)255; return p; };
    _Float16* hF    = (_Float16*)alloc((size_t)64 * NH * 4 * 256 * 2);   // 1.5MB fragment-major
    float*    res   = (float*)alloc((size_t)NN * CALL * 4);
    float*    asrc  = (float*)alloc((size_t)NN * NH * 4);
    float*    adstT = (float*)alloc((size_t)NH * NN * 4);
    _Float16* hsum  = (_Float16*)alloc((size_t)NN * CALL * 2);
    (void)ws_size;

    gemm01<<<dim3(32, 6, 2), dim3(512), 0, stream>>>(x, W, res_W, res_b, attn_src, attn_dst, hF, res, asrc, adstT);
    attn19<<<256, dim3(1024), 0, stream>>>(adj, hF, asrc, adstT, edge_W, edge_b, res, hsum);
    gemm2<<<dim3(32, 6), dim3(512), 0, stream>>>(hsum, fus_W, fus_b, out);
}